// Round 17
// baseline (127.957 us; speedup 1.0000x reference)
//
#include <hip/hip_runtime.h>

#define N_NODES 50000
#define N_EDGES 800000
#define DIM 128
#define NGRAPH 512
#define ODIM 64
#define VOCAB 500
#define NBKT 391              // ceil(50000/128) coarse dst-buckets (128 nodes each)
#define NB2 128               // edge partitions
#define EPB2 (N_EDGES / NB2)  // 6250
#define CAP 4096              // fixed capacity per bucket (mean 2046)

typedef __attribute__((ext_vector_type(8))) short bf16x8;
typedef __attribute__((ext_vector_type(4))) short bf16x4;
typedef __attribute__((ext_vector_type(4))) float f32x4;

__device__ inline unsigned short f2bf(float f) {
  unsigned u = __builtin_bit_cast(unsigned, f);
  return (unsigned short)((u + 0x7fffu + ((u >> 16) & 1u)) >> 16);
}
__device__ inline float bf2f(unsigned short h) {
  unsigned u = ((unsigned)h) << 16;
  return __builtin_bit_cast(float, u);
}

// ---------------------------------------------------------------- prep: emb + weights f32 -> bf16; zero gcnt + pooled
__global__ __launch_bounds__(256) void prep_kernel(
    const float* __restrict__ emb,
    const float* __restrict__ w1a, const float* __restrict__ w1b,
    const float* __restrict__ w2a, const float* __restrict__ w2b,
    unsigned short* __restrict__ embb, unsigned short* __restrict__ wbf,
    int* __restrict__ gcnt, float* __restrict__ pooled) {
  int u = blockIdx.x * 256 + threadIdx.x;   // one bf16x8 unit (8 elems)
  if (u < NBKT) gcnt[u] = 0;
  // zero pooled[NGRAPH*DIM] = 65536 floats
  for (int i = u; i < NGRAPH * DIM; i += 64 * 256) pooled[i] = 0.f;
  const float* src;
  unsigned short* dst;
  if (u < VOCAB * 16) {                     // 8000 units of emb
    src = emb + (size_t)u * 8;
    dst = embb + (size_t)u * 8;
  } else {
    int v = u - VOCAB * 16;                 // 4 x 2048 units of weights
    if (v >= 4 * 2048) return;
    int m = v >> 11, loc = v & 2047;
    const float* w = (m == 0) ? w1a : (m == 1) ? w1b : (m == 2) ? w2a : w2b;
    src = w + (size_t)loc * 8;
    dst = wbf + (size_t)v * 8;
  }
  f32x4 a = ((const f32x4*)src)[0], b = ((const f32x4*)src)[1];
  bf16x8 o;
  #pragma unroll
  for (int e = 0; e < 4; ++e) {
    o[e] = (short)f2bf(a[e]);
    o[4 + e] = (short)f2bf(b[e]);
  }
  *(bf16x8*)dst = o;
}

// ---------------------------------------------------------------- bucket build (single kernel)
__global__ __launch_bounds__(512) void build_kernel(
    const int* __restrict__ ei, int* __restrict__ gcnt,
    unsigned* __restrict__ eb) {
  __shared__ unsigned cnt[NBKT];
  __shared__ unsigned base[NBKT];
  int t = threadIdx.x, b = blockIdx.x;
  for (int i = t; i < NBKT; i += 512) cnt[i] = 0;
  __syncthreads();
  int ebase = b * EPB2;
  for (int i = t; i < EPB2; i += 512)
    atomicAdd(&cnt[(unsigned)ei[N_EDGES + ebase + i] >> 7], 1u);
  __syncthreads();
  for (int i = t; i < NBKT; i += 512) {
    base[i] = (unsigned)atomicAdd(&gcnt[i], (int)cnt[i]);
    cnt[i] = 0;
  }
  __syncthreads();
  for (int i = t; i < EPB2; i += 512) {
    int sn = ei[ebase + i];
    unsigned d = (unsigned)ei[N_EDGES + ebase + i];
    unsigned bk = d >> 7;
    unsigned r = atomicAdd(&cnt[bk], 1u);
    unsigned pos = base[bk] + r;
    if (pos < CAP)
      eb[(size_t)bk * CAP + pos] = ((d & 127u) << 16) | (unsigned)sn;
  }
}

// ---------------------------------------------------------------- sort + conv1-aggregate (fused, 1024 thr)
__global__ __launch_bounds__(1024) void sort_agg1_kernel(
    const unsigned* __restrict__ eb, const int* __restrict__ gcnt,
    const unsigned short* __restrict__ embb, const int* __restrict__ xidx,
    unsigned short* __restrict__ srt16, int* __restrict__ rowlo,
    int* __restrict__ rowhi, unsigned short* __restrict__ xa) {
  __shared__ unsigned stage[CAP];        // 16 KB
  __shared__ unsigned short sorted[CAP]; // 8 KB
  __shared__ unsigned hist[128], cur[128];
  __shared__ unsigned wtot;
  int t = threadIdx.x, bkt = blockIdx.x;
  int cnt = gcnt[bkt];
  if (cnt > CAP) cnt = CAP;
  size_t ebbase = (size_t)bkt * CAP;
  if (t < 128) hist[t] = 0;
  __syncthreads();
  for (int i = t; i < cnt; i += 1024) {
    unsigned e = eb[ebbase + i];
    stage[i] = e;
    atomicAdd(&hist[e >> 16], 1u);
  }
  __syncthreads();
  if (t < 128) {                         // exclusive scan of 128 node counters
    int lane = t & 63;
    unsigned v = hist[t], ss = v;
    #pragma unroll
    for (int d = 1; d < 64; d <<= 1) {
      unsigned u = __shfl_up(ss, d, 64);
      if (lane >= d) ss += u;
    }
    if (t == 63) wtot = ss;
    cur[t] = ss - v;
  }
  __syncthreads();
  if (t < 128) {
    unsigned e0 = cur[t] + (t >= 64 ? wtot : 0u);
    cur[t] = e0;
    int n = bkt * 128 + t;
    if (n < N_NODES) {
      rowlo[n] = (int)(ebbase + e0);
      rowhi[n] = (int)(ebbase + e0 + hist[t]);
    }
  }
  __syncthreads();
  for (int i = t; i < cnt; i += 1024) {
    unsigned e = stage[i];
    unsigned r = atomicAdd(&cur[e >> 16], 1u);
    sorted[r] = (unsigned short)(e & 0xFFFFu);
  }
  __syncthreads();                       // sorted/cur stable from here

  for (int i = t; i < cnt; i += 1024) srt16[ebbase + i] = sorted[i];

  // conv1 aggregation: 64 groups x 16 lanes; 2 iterations cover 128 nodes
  int g = t >> 4, c = t & 15;
  for (int ii = 0; ii < 2; ++ii) {
    int dloc = ii * 64 + g;
    int node = bkt * 128 + dloc;
    if (node >= N_NODES) continue;
    int hi = (int)cur[dloc];
    int lo = hi - (int)hist[dloc];
    bf16x8 sv = *(const bf16x8*)(embb + (size_t)xidx[node] * DIM + c * 8);
    float a[8];
    #pragma unroll
    for (int e = 0; e < 8; ++e) a[e] = bf2f((unsigned short)sv[e]);
    int k = lo;
    for (; k + 8 <= hi; k += 8) {
      bf16x8 w[8];
      #pragma unroll
      for (int q = 0; q < 8; ++q)
        w[q] = *(const bf16x8*)(embb + (size_t)xidx[sorted[k + q]] * DIM + c * 8);
      #pragma unroll
      for (int q = 0; q < 8; ++q)
        #pragma unroll
        for (int e = 0; e < 8; ++e) a[e] += bf2f((unsigned short)w[q][e]);
    }
    for (; k + 2 <= hi; k += 2) {
      bf16x8 w0 = *(const bf16x8*)(embb + (size_t)xidx[sorted[k]] * DIM + c * 8);
      bf16x8 w1 = *(const bf16x8*)(embb + (size_t)xidx[sorted[k + 1]] * DIM + c * 8);
      #pragma unroll
      for (int e = 0; e < 8; ++e)
        a[e] += bf2f((unsigned short)w0[e]) + bf2f((unsigned short)w1[e]);
    }
    if (k < hi) {
      bf16x8 w = *(const bf16x8*)(embb + (size_t)xidx[sorted[k]] * DIM + c * 8);
      #pragma unroll
      for (int e = 0; e < 8; ++e) a[e] += bf2f((unsigned short)w[e]);
    }
    bf16x8 o;
    #pragma unroll
    for (int e = 0; e < 8; ++e) o[e] = (short)f2bf(a[e]);
    *(bf16x8*)(xa + (size_t)node * DIM + c * 8) = o;
  }
}

// ---------------------------------------------------------------- agg (conv2): from node features
__global__ __launch_bounds__(256) void agg_x_kernel(
    const unsigned short* __restrict__ x, const int* __restrict__ rowlo,
    const int* __restrict__ rowhi, const unsigned short* __restrict__ srt16,
    unsigned short* __restrict__ xa) {
  int n = blockIdx.x * 16 + (threadIdx.x >> 4);
  int c = threadIdx.x & 15;
  int lo = rowlo[n], hi = rowhi[n];
  bf16x8 sv = *(const bf16x8*)(x + (size_t)n * DIM + c * 8);
  float a[8];
  #pragma unroll
  for (int e = 0; e < 8; ++e) a[e] = bf2f((unsigned short)sv[e]);
  int k = lo;
  for (; k + 8 <= hi; k += 8) {
    bf16x8 w[8];
    #pragma unroll
    for (int q = 0; q < 8; ++q)
      w[q] = *(const bf16x8*)(x + (size_t)srt16[k + q] * DIM + c * 8);
    #pragma unroll
    for (int q = 0; q < 8; ++q)
      #pragma unroll
      for (int e = 0; e < 8; ++e) a[e] += bf2f((unsigned short)w[q][e]);
  }
  for (; k + 2 <= hi; k += 2) {
    bf16x8 w0 = *(const bf16x8*)(x + (size_t)srt16[k] * DIM + c * 8);
    bf16x8 w1 = *(const bf16x8*)(x + (size_t)srt16[k + 1] * DIM + c * 8);
    #pragma unroll
    for (int e = 0; e < 8; ++e)
      a[e] += bf2f((unsigned short)w0[e]) + bf2f((unsigned short)w1[e]);
  }
  if (k < hi) {
    bf16x8 w = *(const bf16x8*)(x + (size_t)srt16[k] * DIM + c * 8);
    #pragma unroll
    for (int e = 0; e < 8; ++e) a[e] += bf2f((unsigned short)w[e]);
  }
  bf16x8 o;
  #pragma unroll
  for (int e = 0; e < 8; ++e) o[e] = (short)f2bf(a[e]);
  *(bf16x8*)(xa + (size_t)n * DIM + c * 8) = o;
}

// ---------------------------------------------------------------- MLP: 256 thr, 128 nodes (2 halves)
// POOL=0: write bf16 xout. POOL=1: accumulate per-graph f32 sums into pooled (mean-pool fusion).
template <int POOL>
__global__ __launch_bounds__(256) void mlp_mfma_kernel(
    const unsigned short* __restrict__ xa,
    const unsigned short* __restrict__ wabf, const float* __restrict__ ba,
    const unsigned short* __restrict__ wbbf, const float* __restrict__ bb,
    unsigned short* __restrict__ xout, const int* __restrict__ batch,
    float* __restrict__ pooled) {
  __shared__ char smem[65536];               // Xs(16K) | Hs(16K) | pad; Fs overlays all 32K+
  short* Xs = (short*)smem;                  // [64][128] bf16, XOR swizzle
  short* Hs = (short*)(smem + 32768);        // [64][128] bf16, XOR swizzle
  float* Fs = (float*)smem;                  // [64][128] f32 overlay (POOL epilogue)
  int t = threadIdx.x;
  int lane = t & 63;
  int w = t >> 6;
  int jq = w * 32;
  int l15 = lane & 15;
  int lg = lane >> 4;

  bf16x8 waf[2][4], wbf[2][4];
  #pragma unroll
  for (int jm = 0; jm < 2; ++jm) {
    int jrow = jq + jm * 16 + l15;
    #pragma unroll
    for (int ks = 0; ks < 4; ++ks) {
      int k0 = ks * 32 + lg * 8;
      waf[jm][ks] = *(const bf16x8*)(wabf + (size_t)jrow * DIM + k0);
      wbf[jm][ks] = *(const bf16x8*)(wbbf + (size_t)jrow * DIM + k0);
    }
  }
  f32x4 ba_r[2], bb_r[2];
  #pragma unroll
  for (int jm = 0; jm < 2; ++jm) {
    ba_r[jm] = *(const f32x4*)(ba + jq + jm * 16 + lg * 4);
    bb_r[jm] = *(const f32x4*)(bb + jq + jm * 16 + lg * 4);
  }

  for (int half = 0; half < 2; ++half) {
    int nbase = blockIdx.x * 128 + half * 64;

    {
      int r = t >> 2;
      int cb = (t & 3) * 4;
      int node = nbase + r;
      #pragma unroll
      for (int i = 0; i < 4; ++i) {
        int chunk = cb + i;
        bf16x8 v = {0, 0, 0, 0, 0, 0, 0, 0};
        if (node < N_NODES)
          v = *(const bf16x8*)(xa + (size_t)node * DIM + chunk * 8);
        *(bf16x8*)&Xs[r * 128 + ((chunk ^ (r & 7)) << 3)] = v;
      }
    }
    __syncthreads();

    f32x4 acc2[4][2];   // POOL epilogue needs all GEMM2 results before overlay write
    #pragma unroll
    for (int nt = 0; nt < 4; ++nt) {
      int rrow = nt * 16 + l15;
      bf16x8 xf[4];
      #pragma unroll
      for (int ks = 0; ks < 4; ++ks) {
        int chunk = ks * 4 + lg;
        xf[ks] = *(const bf16x8*)&Xs[rrow * 128 + ((chunk ^ (rrow & 7)) << 3)];
      }
      #pragma unroll
      for (int jm = 0; jm < 2; ++jm) {
        f32x4 acc = ba_r[jm];
        #pragma unroll
        for (int ks = 0; ks < 4; ++ks)
          acc = __builtin_amdgcn_mfma_f32_16x16x32_bf16(waf[jm][ks], xf[ks], acc, 0, 0, 0);
        int hnode = nt * 16 + l15;
        int cbase = jq + jm * 16 + lg * 4;
        unsigned p0 = (unsigned)f2bf(fmaxf(acc[0], 0.f)) |
                      ((unsigned)f2bf(fmaxf(acc[1], 0.f)) << 16);
        unsigned p1 = (unsigned)f2bf(fmaxf(acc[2], 0.f)) |
                      ((unsigned)f2bf(fmaxf(acc[3], 0.f)) << 16);
        unsigned idx = hnode * 128 + (((cbase >> 3) ^ (hnode & 7)) << 3) + (cbase & 7);
        *(uint2*)&Hs[idx] = make_uint2(p0, p1);
      }
    }
    __syncthreads();

    #pragma unroll
    for (int nt = 0; nt < 4; ++nt) {
      int rrow = nt * 16 + l15;
      bf16x8 hf[4];
      #pragma unroll
      for (int ks = 0; ks < 4; ++ks) {
        int chunk = ks * 4 + lg;
        hf[ks] = *(const bf16x8*)&Hs[rrow * 128 + ((chunk ^ (rrow & 7)) << 3)];
      }
      #pragma unroll
      for (int jm = 0; jm < 2; ++jm) {
        f32x4 acc = bb_r[jm];
        #pragma unroll
        for (int ks = 0; ks < 4; ++ks)
          acc = __builtin_amdgcn_mfma_f32_16x16x32_bf16(wbf[jm][ks], hf[ks], acc, 0, 0, 0);
        if (POOL == 0) {
          int node = nbase + rrow;
          if (node < N_NODES) {
            bf16x4 o;
            #pragma unroll
            for (int e = 0; e < 4; ++e) o[e] = (short)f2bf(fmaxf(acc[e], 0.f));
            *(bf16x4*)(xout + (size_t)node * DIM + jq + jm * 16 + lg * 4) = o;
          }
        } else {
          acc2[nt][jm] = acc;
        }
      }
    }

    if (POOL == 1) {
      __syncthreads();   // all Hs reads done; safe to overlay Fs
      #pragma unroll
      for (int nt = 0; nt < 4; ++nt) {
        int rrow = nt * 16 + l15;
        #pragma unroll
        for (int jm = 0; jm < 2; ++jm) {
          int cbase = jq + jm * 16 + lg * 4;
          #pragma unroll
          for (int e = 0; e < 4; ++e)
            Fs[rrow * 128 + cbase + e] = fmaxf(acc2[nt][jm][e], 0.f);
        }
      }
      __syncthreads();
      // per-graph reduce: 256 thr = 2 node-halves x 128 dims; batch sorted
      int d = t & 127;
      int h = t >> 7;                        // 0,1 -> nodes [h*32, h*32+32)
      float s = 0.f;
      int curg = -1;
      for (int nn = h * 32; nn < h * 32 + 32; ++nn) {
        int node = nbase + nn;
        if (node >= N_NODES) break;
        int gg = batch[node];
        if (gg != curg) {
          if (curg >= 0 && s != 0.f) atomicAdd(&pooled[curg * DIM + d], s);
          curg = gg; s = 0.f;
        }
        s += Fs[nn * 128 + d];
      }
      if (curg >= 0 && s != 0.f) atomicAdd(&pooled[curg * DIM + d], s);
    }
    __syncthreads();   // protect smem before next half
  }
}

// ---------------------------------------------------------------- FC over pooled means
__global__ __launch_bounds__(64) void fc_kernel(
    const float* __restrict__ pooled, const int* __restrict__ batch,
    const float* __restrict__ fcw, const float* __restrict__ fcb,
    float* __restrict__ out) {
  int g = blockIdx.x, t = threadIdx.x;
  __shared__ int sb[2];
  if (t < 2) {
    int target = g + t;
    int lo = 0, hi = N_NODES;
    while (lo < hi) {
      int m = (lo + hi) >> 1;
      if (batch[m] < target) lo = m + 1; else hi = m;
    }
    sb[t] = lo;
  }
  __syncthreads();
  float inv = 1.f / fmaxf((float)(sb[1] - sb[0]), 1.0f);
  float a = fcb[t];
  const float* pr = pooled + (size_t)g * DIM;
  const float* wr = fcw + (size_t)t * DIM;
  #pragma unroll 8
  for (int h = 0; h < DIM; ++h) a += pr[h] * inv * wr[h];
  out[(size_t)g * ODIM + t] = a;
}

// ---------------------------------------------------------------- launch
extern "C" void kernel_launch(void* const* d_in, const int* in_sizes, int n_in,
                              void* d_out, int out_size, void* d_ws, size_t ws_size,
                              hipStream_t stream) {
  const float* emb  = (const float*)d_in[0];
  const float* w1a  = (const float*)d_in[1];
  const float* b1a  = (const float*)d_in[2];
  const float* w1b  = (const float*)d_in[3];
  const float* b1b  = (const float*)d_in[4];
  const float* w2a  = (const float*)d_in[5];
  const float* b2a  = (const float*)d_in[6];
  const float* w2b  = (const float*)d_in[7];
  const float* b2b  = (const float*)d_in[8];
  const float* fcw  = (const float*)d_in[9];
  const float* fcb  = (const float*)d_in[10];
  const int*   xidx = (const int*)d_in[11];
  const int*   ei   = (const int*)d_in[12];
  const int*   batch= (const int*)d_in[13];
  float* out = (float*)d_out;

  size_t featb = (size_t)N_NODES * DIM * sizeof(unsigned short);  // 12.8 MB
  char* ws = (char*)d_ws;
  unsigned short* B1 = (unsigned short*)ws;             // agg buffer
  unsigned short* B2 = (unsigned short*)(ws + featb);   // conv1 out
  char* p = ws + 2 * featb;
  unsigned short* embb = (unsigned short*)p;  p += (VOCAB * DIM * 2 + 15) / 16 * 16;
  unsigned short* wbf  = (unsigned short*)p;  p += (4 * DIM * DIM * 2 + 15) / 16 * 16;  // 128 KB
  int* gcnt  = (int*)p;     p += (NBKT * 4 + 15) / 16 * 16;
  int* rowlo = (int*)p;     p += ((size_t)N_NODES * 4 + 15) / 16 * 16;
  int* rowhi = (int*)p;     p += ((size_t)N_NODES * 4 + 15) / 16 * 16;
  float* pooled = (float*)p; p += (size_t)NGRAPH * DIM * 4;            // 256 KB
  unsigned* eb = (unsigned*)p;          p += (size_t)NBKT * CAP * 4;   // 6.4 MB
  unsigned short* srt16 = (unsigned short*)p;                          // 3.2 MB

  const unsigned short* w1abf = wbf;
  const unsigned short* w1bbf = wbf + DIM * DIM;
  const unsigned short* w2abf = wbf + 2 * DIM * DIM;
  const unsigned short* w2bbf = wbf + 3 * DIM * DIM;

  prep_kernel<<<(VOCAB * 16 + 4 * 2048 + 255) / 256, 256, 0, stream>>>(
      emb, w1a, w1b, w2a, w2b, embb, wbf, gcnt, pooled);

  // bucket build (count -> span-alloc -> scatter) in ONE kernel
  build_kernel<<<NB2, 512, 0, stream>>>(ei, gcnt, eb);

  // sort buckets + conv1 aggregation fused (1024 thr)
  sort_agg1_kernel<<<NBKT, 1024, 0, stream>>>(eb, gcnt, embb, xidx, srt16, rowlo, rowhi, B1);
  mlp_mfma_kernel<0><<<(N_NODES + 127) / 128, 256, 0, stream>>>(
      B1, w1abf, b1a, w1bbf, b1b, B2, batch, pooled);

  // conv2: gather from node features, then MLP with fused mean-pool accumulation
  agg_x_kernel<<<N_NODES / 16, 256, 0, stream>>>(B2, rowlo, rowhi, srt16, B1);
  mlp_mfma_kernel<1><<<(N_NODES + 127) / 128, 256, 0, stream>>>(
      B1, w2abf, b2a, w2bbf, b2b, nullptr, batch, pooled);

  fc_kernel<<<NGRAPH, 64, 0, stream>>>(pooled, batch, fcw, fcb, out);
}

// Round 18
// 127.305 us; speedup vs baseline: 1.0051x; 1.0051x over previous
//
#include <hip/hip_runtime.h>

#define N_NODES 50000
#define N_EDGES 800000
#define DIM 128
#define NGRAPH 512
#define ODIM 64
#define VOCAB 500
#define NBKT 391              // ceil(50000/128) coarse dst-buckets (128 nodes each)
#define NB2 128               // edge partitions
#define EPB2 (N_EDGES / NB2)  // 6250
#define CAP 4096              // fixed capacity per bucket (mean 2046)

typedef __attribute__((ext_vector_type(8))) short bf16x8;
typedef __attribute__((ext_vector_type(4))) short bf16x4;
typedef __attribute__((ext_vector_type(4))) float f32x4;

__device__ inline unsigned short f2bf(float f) {
  unsigned u = __builtin_bit_cast(unsigned, f);
  return (unsigned short)((u + 0x7fffu + ((u >> 16) & 1u)) >> 16);
}
__device__ inline float bf2f(unsigned short h) {
  unsigned u = ((unsigned)h) << 16;
  return __builtin_bit_cast(float, u);
}

// ---------------------------------------------------------------- prep: emb + weights f32 -> bf16; zero gcnt + pooled
__global__ __launch_bounds__(256) void prep_kernel(
    const float* __restrict__ emb,
    const float* __restrict__ w1a, const float* __restrict__ w1b,
    const float* __restrict__ w2a, const float* __restrict__ w2b,
    unsigned short* __restrict__ embb, unsigned short* __restrict__ wbf,
    int* __restrict__ gcnt, float* __restrict__ pooled) {
  int u = blockIdx.x * 256 + threadIdx.x;   // one bf16x8 unit (8 elems)
  if (u < NBKT) gcnt[u] = 0;
  for (int i = u; i < NGRAPH * DIM; i += 64 * 256) pooled[i] = 0.f;
  const float* src;
  unsigned short* dst;
  if (u < VOCAB * 16) {                     // 8000 units of emb
    src = emb + (size_t)u * 8;
    dst = embb + (size_t)u * 8;
  } else {
    int v = u - VOCAB * 16;                 // 4 x 2048 units of weights
    if (v >= 4 * 2048) return;
    int m = v >> 11, loc = v & 2047;
    const float* w = (m == 0) ? w1a : (m == 1) ? w1b : (m == 2) ? w2a : w2b;
    src = w + (size_t)loc * 8;
    dst = wbf + (size_t)v * 8;
  }
  f32x4 a = ((const f32x4*)src)[0], b = ((const f32x4*)src)[1];
  bf16x8 o;
  #pragma unroll
  for (int e = 0; e < 4; ++e) {
    o[e] = (short)f2bf(a[e]);
    o[4 + e] = (short)f2bf(b[e]);
  }
  *(bf16x8*)dst = o;
}

// ---------------------------------------------------------------- bucket build (single kernel)
__global__ __launch_bounds__(512) void build_kernel(
    const int* __restrict__ ei, int* __restrict__ gcnt,
    unsigned* __restrict__ eb) {
  __shared__ unsigned cnt[NBKT];
  __shared__ unsigned base[NBKT];
  int t = threadIdx.x, b = blockIdx.x;
  for (int i = t; i < NBKT; i += 512) cnt[i] = 0;
  __syncthreads();
  int ebase = b * EPB2;
  for (int i = t; i < EPB2; i += 512)
    atomicAdd(&cnt[(unsigned)ei[N_EDGES + ebase + i] >> 7], 1u);
  __syncthreads();
  for (int i = t; i < NBKT; i += 512) {
    base[i] = (unsigned)atomicAdd(&gcnt[i], (int)cnt[i]);
    cnt[i] = 0;
  }
  __syncthreads();
  for (int i = t; i < EPB2; i += 512) {
    int sn = ei[ebase + i];
    unsigned d = (unsigned)ei[N_EDGES + ebase + i];
    unsigned bk = d >> 7;
    unsigned r = atomicAdd(&cnt[bk], 1u);
    unsigned pos = base[bk] + r;
    if (pos < CAP)
      eb[(size_t)bk * CAP + pos] = ((d & 127u) << 16) | (unsigned)sn;
  }
}

// ---------------------------------------------------------------- sort + conv1-aggregate (fused, 512 thr)
__global__ __launch_bounds__(512) void sort_agg1_kernel(
    const unsigned* __restrict__ eb, const int* __restrict__ gcnt,
    const unsigned short* __restrict__ embb, const int* __restrict__ xidx,
    unsigned short* __restrict__ srt16, int* __restrict__ rowlo,
    int* __restrict__ rowhi, unsigned short* __restrict__ xa) {
  __shared__ unsigned stage[CAP];        // 16 KB
  __shared__ unsigned short sorted[CAP]; // 8 KB
  __shared__ unsigned hist[128], cur[128];
  __shared__ unsigned wtot;
  int t = threadIdx.x, bkt = blockIdx.x;
  int cnt = gcnt[bkt];
  if (cnt > CAP) cnt = CAP;
  size_t ebbase = (size_t)bkt * CAP;
  if (t < 128) hist[t] = 0;
  __syncthreads();
  for (int i = t; i < cnt; i += 512) {
    unsigned e = eb[ebbase + i];
    stage[i] = e;
    atomicAdd(&hist[e >> 16], 1u);
  }
  __syncthreads();
  if (t < 128) {                         // exclusive scan of 128 node counters
    int lane = t & 63;
    unsigned v = hist[t], ss = v;
    #pragma unroll
    for (int d = 1; d < 64; d <<= 1) {
      unsigned u = __shfl_up(ss, d, 64);
      if (lane >= d) ss += u;
    }
    if (t == 63) wtot = ss;
    cur[t] = ss - v;
  }
  __syncthreads();
  if (t < 128) {
    unsigned e0 = cur[t] + (t >= 64 ? wtot : 0u);
    cur[t] = e0;
    int n = bkt * 128 + t;
    if (n < N_NODES) {
      rowlo[n] = (int)(ebbase + e0);
      rowhi[n] = (int)(ebbase + e0 + hist[t]);
    }
  }
  __syncthreads();
  for (int i = t; i < cnt; i += 512) {
    unsigned e = stage[i];
    unsigned r = atomicAdd(&cur[e >> 16], 1u);
    sorted[r] = (unsigned short)(e & 0xFFFFu);
  }
  __syncthreads();                       // sorted/cur stable from here

  for (int i = t; i < cnt; i += 512) srt16[ebbase + i] = sorted[i];

  // conv1 aggregation: 32 groups x 16 lanes; 4 iterations cover 128 nodes
  int g = t >> 4, c = t & 15;
  for (int ii = 0; ii < 4; ++ii) {
    int dloc = ii * 32 + g;
    int node = bkt * 128 + dloc;
    if (node >= N_NODES) continue;
    int hi = (int)cur[dloc];
    int lo = hi - (int)hist[dloc];
    bf16x8 sv = *(const bf16x8*)(embb + (size_t)xidx[node] * DIM + c * 8);
    float a[8];
    #pragma unroll
    for (int e = 0; e < 8; ++e) a[e] = bf2f((unsigned short)sv[e]);
    int k = lo;
    for (; k + 8 <= hi; k += 8) {
      bf16x8 w[8];
      #pragma unroll
      for (int q = 0; q < 8; ++q)
        w[q] = *(const bf16x8*)(embb + (size_t)xidx[sorted[k + q]] * DIM + c * 8);
      #pragma unroll
      for (int q = 0; q < 8; ++q)
        #pragma unroll
        for (int e = 0; e < 8; ++e) a[e] += bf2f((unsigned short)w[q][e]);
    }
    for (; k + 2 <= hi; k += 2) {
      bf16x8 w0 = *(const bf16x8*)(embb + (size_t)xidx[sorted[k]] * DIM + c * 8);
      bf16x8 w1 = *(const bf16x8*)(embb + (size_t)xidx[sorted[k + 1]] * DIM + c * 8);
      #pragma unroll
      for (int e = 0; e < 8; ++e)
        a[e] += bf2f((unsigned short)w0[e]) + bf2f((unsigned short)w1[e]);
    }
    if (k < hi) {
      bf16x8 w = *(const bf16x8*)(embb + (size_t)xidx[sorted[k]] * DIM + c * 8);
      #pragma unroll
      for (int e = 0; e < 8; ++e) a[e] += bf2f((unsigned short)w[e]);
    }
    bf16x8 o;
    #pragma unroll
    for (int e = 0; e < 8; ++e) o[e] = (short)f2bf(a[e]);
    *(bf16x8*)(xa + (size_t)node * DIM + c * 8) = o;
  }
}

// ---------------------------------------------------------------- agg (conv2): from node features
__global__ __launch_bounds__(256) void agg_x_kernel(
    const unsigned short* __restrict__ x, const int* __restrict__ rowlo,
    const int* __restrict__ rowhi, const unsigned short* __restrict__ srt16,
    unsigned short* __restrict__ xa) {
  int n = blockIdx.x * 16 + (threadIdx.x >> 4);
  int c = threadIdx.x & 15;
  int lo = rowlo[n], hi = rowhi[n];
  bf16x8 sv = *(const bf16x8*)(x + (size_t)n * DIM + c * 8);
  float a[8];
  #pragma unroll
  for (int e = 0; e < 8; ++e) a[e] = bf2f((unsigned short)sv[e]);
  int k = lo;
  for (; k + 8 <= hi; k += 8) {
    bf16x8 w[8];
    #pragma unroll
    for (int q = 0; q < 8; ++q)
      w[q] = *(const bf16x8*)(x + (size_t)srt16[k + q] * DIM + c * 8);
    #pragma unroll
    for (int q = 0; q < 8; ++q)
      #pragma unroll
      for (int e = 0; e < 8; ++e) a[e] += bf2f((unsigned short)w[q][e]);
  }
  for (; k + 2 <= hi; k += 2) {
    bf16x8 w0 = *(const bf16x8*)(x + (size_t)srt16[k] * DIM + c * 8);
    bf16x8 w1 = *(const bf16x8*)(x + (size_t)srt16[k + 1] * DIM + c * 8);
    #pragma unroll
    for (int e = 0; e < 8; ++e)
      a[e] += bf2f((unsigned short)w0[e]) + bf2f((unsigned short)w1[e]);
  }
  if (k < hi) {
    bf16x8 w = *(const bf16x8*)(x + (size_t)srt16[k] * DIM + c * 8);
    #pragma unroll
    for (int e = 0; e < 8; ++e) a[e] += bf2f((unsigned short)w[e]);
  }
  bf16x8 o;
  #pragma unroll
  for (int e = 0; e < 8; ++e) o[e] = (short)f2bf(a[e]);
  *(bf16x8*)(xa + (size_t)n * DIM + c * 8) = o;
}

// ---------------------------------------------------------------- MLP: 256 thr, 128 nodes (2 halves)
// POOL=0: write bf16 xout. POOL=1: accumulate per-graph f32 sums into pooled.
// LDS: 32 KB total. Xs@0 (16K), Hs@16K (16K); Fs (f32 [64][128] = 32K) overlays both.
template <int POOL>
__global__ __launch_bounds__(256) void mlp_mfma_kernel(
    const unsigned short* __restrict__ xa,
    const unsigned short* __restrict__ wabf, const float* __restrict__ ba,
    const unsigned short* __restrict__ wbbf, const float* __restrict__ bb,
    unsigned short* __restrict__ xout, const int* __restrict__ batch,
    float* __restrict__ pooled) {
  __shared__ char smem[32768];
  short* Xs = (short*)smem;                  // [64][128] bf16, XOR swizzle
  short* Hs = (short*)(smem + 16384);        // [64][128] bf16, XOR swizzle
  float* Fs = (float*)smem;                  // [64][128] f32 overlay (POOL epilogue)
  int t = threadIdx.x;
  int lane = t & 63;
  int w = t >> 6;
  int jq = w * 32;
  int l15 = lane & 15;
  int lg = lane >> 4;

  bf16x8 waf[2][4], wbf[2][4];
  #pragma unroll
  for (int jm = 0; jm < 2; ++jm) {
    int jrow = jq + jm * 16 + l15;
    #pragma unroll
    for (int ks = 0; ks < 4; ++ks) {
      int k0 = ks * 32 + lg * 8;
      waf[jm][ks] = *(const bf16x8*)(wabf + (size_t)jrow * DIM + k0);
      wbf[jm][ks] = *(const bf16x8*)(wbbf + (size_t)jrow * DIM + k0);
    }
  }
  f32x4 ba_r[2], bb_r[2];
  #pragma unroll
  for (int jm = 0; jm < 2; ++jm) {
    ba_r[jm] = *(const f32x4*)(ba + jq + jm * 16 + lg * 4);
    bb_r[jm] = *(const f32x4*)(bb + jq + jm * 16 + lg * 4);
  }

  for (int half = 0; half < 2; ++half) {
    int nbase = blockIdx.x * 128 + half * 64;

    {
      int r = t >> 2;
      int cb = (t & 3) * 4;
      int node = nbase + r;
      #pragma unroll
      for (int i = 0; i < 4; ++i) {
        int chunk = cb + i;
        bf16x8 v = {0, 0, 0, 0, 0, 0, 0, 0};
        if (node < N_NODES)
          v = *(const bf16x8*)(xa + (size_t)node * DIM + chunk * 8);
        *(bf16x8*)&Xs[r * 128 + ((chunk ^ (r & 7)) << 3)] = v;
      }
    }
    __syncthreads();

    f32x4 acc2[4][2];
    #pragma unroll
    for (int nt = 0; nt < 4; ++nt) {
      int rrow = nt * 16 + l15;
      bf16x8 xf[4];
      #pragma unroll
      for (int ks = 0; ks < 4; ++ks) {
        int chunk = ks * 4 + lg;
        xf[ks] = *(const bf16x8*)&Xs[rrow * 128 + ((chunk ^ (rrow & 7)) << 3)];
      }
      #pragma unroll
      for (int jm = 0; jm < 2; ++jm) {
        f32x4 acc = ba_r[jm];
        #pragma unroll
        for (int ks = 0; ks < 4; ++ks)
          acc = __builtin_amdgcn_mfma_f32_16x16x32_bf16(waf[jm][ks], xf[ks], acc, 0, 0, 0);
        int hnode = nt * 16 + l15;
        int cbase = jq + jm * 16 + lg * 4;
        unsigned p0 = (unsigned)f2bf(fmaxf(acc[0], 0.f)) |
                      ((unsigned)f2bf(fmaxf(acc[1], 0.f)) << 16);
        unsigned p1 = (unsigned)f2bf(fmaxf(acc[2], 0.f)) |
                      ((unsigned)f2bf(fmaxf(acc[3], 0.f)) << 16);
        unsigned idx = hnode * 128 + (((cbase >> 3) ^ (hnode & 7)) << 3) + (cbase & 7);
        *(uint2*)&Hs[idx] = make_uint2(p0, p1);
      }
    }
    __syncthreads();

    #pragma unroll
    for (int nt = 0; nt < 4; ++nt) {
      int rrow = nt * 16 + l15;
      bf16x8 hf[4];
      #pragma unroll
      for (int ks = 0; ks < 4; ++ks) {
        int chunk = ks * 4 + lg;
        hf[ks] = *(const bf16x8*)&Hs[rrow * 128 + ((chunk ^ (rrow & 7)) << 3)];
      }
      #pragma unroll
      for (int jm = 0; jm < 2; ++jm) {
        f32x4 acc = bb_r[jm];
        #pragma unroll
        for (int ks = 0; ks < 4; ++ks)
          acc = __builtin_amdgcn_mfma_f32_16x16x32_bf16(wbf[jm][ks], hf[ks], acc, 0, 0, 0);
        if (POOL == 0) {
          int node = nbase + rrow;
          if (node < N_NODES) {
            bf16x4 o;
            #pragma unroll
            for (int e = 0; e < 4; ++e) o[e] = (short)f2bf(fmaxf(acc[e], 0.f));
            *(bf16x4*)(xout + (size_t)node * DIM + jq + jm * 16 + lg * 4) = o;
          }
        } else {
          acc2[nt][jm] = acc;
        }
      }
    }

    if (POOL == 1) {
      __syncthreads();   // all Hs reads done; safe to overlay Fs
      #pragma unroll
      for (int nt = 0; nt < 4; ++nt) {
        int rrow = nt * 16 + l15;
        #pragma unroll
        for (int jm = 0; jm < 2; ++jm) {
          int cbase = jq + jm * 16 + lg * 4;
          #pragma unroll
          for (int e = 0; e < 4; ++e)
            Fs[rrow * 128 + cbase + e] = fmaxf(acc2[nt][jm][e], 0.f);
        }
      }
      __syncthreads();
      // per-graph reduce: 256 thr = 2 node-halves x 128 dims; batch sorted
      int d = t & 127;
      int h = t >> 7;
      float s = 0.f;
      int curg = -1;
      for (int nn = h * 32; nn < h * 32 + 32; ++nn) {
        int node = nbase + nn;
        if (node >= N_NODES) break;
        int gg = batch[node];
        if (gg != curg) {
          if (curg >= 0 && s != 0.f) atomicAdd(&pooled[curg * DIM + d], s);
          curg = gg; s = 0.f;
        }
        s += Fs[nn * 128 + d];
      }
      if (curg >= 0 && s != 0.f) atomicAdd(&pooled[curg * DIM + d], s);
    }
    __syncthreads();   // protect smem before next half
  }
}

// ---------------------------------------------------------------- FC over pooled means
__global__ __launch_bounds__(64) void fc_kernel(
    const float* __restrict__ pooled, const int* __restrict__ batch,
    const float* __restrict__ fcw, const float* __restrict__ fcb,
    float* __restrict__ out) {
  int g = blockIdx.x, t = threadIdx.x;
  __shared__ int sb[2];
  if (t < 2) {
    int target = g + t;
    int lo = 0, hi = N_NODES;
    while (lo < hi) {
      int m = (lo + hi) >> 1;
      if (batch[m] < target) lo = m + 1; else hi = m;
    }
    sb[t] = lo;
  }
  __syncthreads();
  float inv = 1.f / fmaxf((float)(sb[1] - sb[0]), 1.0f);
  float a = fcb[t];
  const float* pr = pooled + (size_t)g * DIM;
  const float* wr = fcw + (size_t)t * DIM;
  #pragma unroll 8
  for (int h = 0; h < DIM; ++h) a += pr[h] * inv * wr[h];
  out[(size_t)g * ODIM + t] = a;
}

// ---------------------------------------------------------------- launch
extern "C" void kernel_launch(void* const* d_in, const int* in_sizes, int n_in,
                              void* d_out, int out_size, void* d_ws, size_t ws_size,
                              hipStream_t stream) {
  const float* emb  = (const float*)d_in[0];
  const float* w1a  = (const float*)d_in[1];
  const float* b1a  = (const float*)d_in[2];
  const float* w1b  = (const float*)d_in[3];
  const float* b1b  = (const float*)d_in[4];
  const float* w2a  = (const float*)d_in[5];
  const float* b2a  = (const float*)d_in[6];
  const float* w2b  = (const float*)d_in[7];
  const float* b2b  = (const float*)d_in[8];
  const float* fcw  = (const float*)d_in[9];
  const float* fcb  = (const float*)d_in[10];
  const int*   xidx = (const int*)d_in[11];
  const int*   ei   = (const int*)d_in[12];
  const int*   batch= (const int*)d_in[13];
  float* out = (float*)d_out;

  size_t featb = (size_t)N_NODES * DIM * sizeof(unsigned short);  // 12.8 MB
  char* ws = (char*)d_ws;
  unsigned short* B1 = (unsigned short*)ws;             // agg buffer
  unsigned short* B2 = (unsigned short*)(ws + featb);   // conv1 out
  char* p = ws + 2 * featb;
  unsigned short* embb = (unsigned short*)p;  p += (VOCAB * DIM * 2 + 15) / 16 * 16;
  unsigned short* wbf  = (unsigned short*)p;  p += (4 * DIM * DIM * 2 + 15) / 16 * 16;  // 128 KB
  int* gcnt  = (int*)p;     p += (NBKT * 4 + 15) / 16 * 16;
  int* rowlo = (int*)p;     p += ((size_t)N_NODES * 4 + 15) / 16 * 16;
  int* rowhi = (int*)p;     p += ((size_t)N_NODES * 4 + 15) / 16 * 16;
  float* pooled = (float*)p; p += (size_t)NGRAPH * DIM * 4;            // 256 KB
  unsigned* eb = (unsigned*)p;          p += (size_t)NBKT * CAP * 4;   // 6.4 MB
  unsigned short* srt16 = (unsigned short*)p;                          // 3.2 MB

  const unsigned short* w1abf = wbf;
  const unsigned short* w1bbf = wbf + DIM * DIM;
  const unsigned short* w2abf = wbf + 2 * DIM * DIM;
  const unsigned short* w2bbf = wbf + 3 * DIM * DIM;

  prep_kernel<<<(VOCAB * 16 + 4 * 2048 + 255) / 256, 256, 0, stream>>>(
      emb, w1a, w1b, w2a, w2b, embb, wbf, gcnt, pooled);

  // bucket build (count -> span-alloc -> scatter) in ONE kernel
  build_kernel<<<NB2, 512, 0, stream>>>(ei, gcnt, eb);

  // sort buckets + conv1 aggregation fused (512 thr)
  sort_agg1_kernel<<<NBKT, 512, 0, stream>>>(eb, gcnt, embb, xidx, srt16, rowlo, rowhi, B1);
  mlp_mfma_kernel<0><<<(N_NODES + 127) / 128, 256, 0, stream>>>(
      B1, w1abf, b1a, w1bbf, b1b, B2, batch, pooled);

  // conv2: gather from node features, then MLP with fused mean-pool accumulation
  agg_x_kernel<<<N_NODES / 16, 256, 0, stream>>>(B2, rowlo, rowhi, srt16, B1);
  mlp_mfma_kernel<1><<<(N_NODES + 127) / 128, 256, 0, stream>>>(
      B1, w2abf, b2a, w2bbf, b2b, nullptr, batch, pooled);

  fc_kernel<<<NGRAPH, 64, 0, stream>>>(pooled, batch, fcw, fcb, out);
}

// Round 19
// 120.727 us; speedup vs baseline: 1.0599x; 1.0545x over previous
//
#include <hip/hip_runtime.h>

#define N_NODES 50000
#define N_EDGES 800000
#define DIM 128
#define NGRAPH 512
#define ODIM 64
#define VOCAB 500
#define NBKT 391              // ceil(50000/128) coarse dst-buckets (128 nodes each)
#define NB2 128               // edge partitions
#define EPB2 (N_EDGES / NB2)  // 6250
#define CAP 4096              // fixed capacity per bucket (mean 2046)

typedef __attribute__((ext_vector_type(8))) short bf16x8;
typedef __attribute__((ext_vector_type(4))) short bf16x4;
typedef __attribute__((ext_vector_type(4))) float f32x4;

__device__ inline unsigned short f2bf(float f) {
  unsigned u = __builtin_bit_cast(unsigned, f);
  return (unsigned short)((u + 0x7fffu + ((u >> 16) & 1u)) >> 16);
}
__device__ inline float bf2f(unsigned short h) {
  unsigned u = ((unsigned)h) << 16;
  return __builtin_bit_cast(float, u);
}

// ---------------------------------------------------------------- prep: emb + weights f32 -> bf16; zero gcnt
__global__ __launch_bounds__(256) void prep_kernel(
    const float* __restrict__ emb,
    const float* __restrict__ w1a, const float* __restrict__ w1b,
    const float* __restrict__ w2a, const float* __restrict__ w2b,
    unsigned short* __restrict__ embb, unsigned short* __restrict__ wbf,
    int* __restrict__ gcnt) {
  int u = blockIdx.x * 256 + threadIdx.x;   // one bf16x8 unit (8 elems)
  if (u < NBKT) gcnt[u] = 0;
  const float* src;
  unsigned short* dst;
  if (u < VOCAB * 16) {                     // 8000 units of emb
    src = emb + (size_t)u * 8;
    dst = embb + (size_t)u * 8;
  } else {
    int v = u - VOCAB * 16;                 // 4 x 2048 units of weights
    if (v >= 4 * 2048) return;
    int m = v >> 11, loc = v & 2047;
    const float* w = (m == 0) ? w1a : (m == 1) ? w1b : (m == 2) ? w2a : w2b;
    src = w + (size_t)loc * 8;
    dst = wbf + (size_t)v * 8;
  }
  f32x4 a = ((const f32x4*)src)[0], b = ((const f32x4*)src)[1];
  bf16x8 o;
  #pragma unroll
  for (int e = 0; e < 4; ++e) {
    o[e] = (short)f2bf(a[e]);
    o[4 + e] = (short)f2bf(b[e]);
  }
  *(bf16x8*)dst = o;
}

// ---------------------------------------------------------------- bucket build (single kernel)
// count in LDS -> one global atomicAdd per bucket to allocate span -> scatter with LDS ranks
__global__ __launch_bounds__(512) void build_kernel(
    const int* __restrict__ ei, int* __restrict__ gcnt,
    unsigned* __restrict__ eb) {
  __shared__ unsigned cnt[NBKT];
  __shared__ unsigned base[NBKT];
  int t = threadIdx.x, b = blockIdx.x;
  for (int i = t; i < NBKT; i += 512) cnt[i] = 0;
  __syncthreads();
  int ebase = b * EPB2;
  for (int i = t; i < EPB2; i += 512)
    atomicAdd(&cnt[(unsigned)ei[N_EDGES + ebase + i] >> 7], 1u);
  __syncthreads();
  for (int i = t; i < NBKT; i += 512) {
    base[i] = (unsigned)atomicAdd(&gcnt[i], (int)cnt[i]);
    cnt[i] = 0;
  }
  __syncthreads();
  for (int i = t; i < EPB2; i += 512) {
    int sn = ei[ebase + i];
    unsigned d = (unsigned)ei[N_EDGES + ebase + i];
    unsigned bk = d >> 7;
    unsigned r = atomicAdd(&cnt[bk], 1u);
    unsigned pos = base[bk] + r;
    if (pos < CAP)
      eb[(size_t)bk * CAP + pos] = ((d & 127u) << 16) | (unsigned)sn;
  }
}

// ---------------------------------------------------------------- sort + conv1-aggregate (fused)
// per bucket: LDS counting sort by dloc; emit srt16/rowlo/rowhi for conv2;
// then aggregate 128 nodes from the L2-resident emb table using LDS-sorted lists.
__global__ __launch_bounds__(512) void sort_agg1_kernel(
    const unsigned* __restrict__ eb, const int* __restrict__ gcnt,
    const unsigned short* __restrict__ embb, const int* __restrict__ xidx,
    unsigned short* __restrict__ srt16, int* __restrict__ rowlo,
    int* __restrict__ rowhi, unsigned short* __restrict__ xa) {
  __shared__ unsigned stage[CAP];        // 16 KB
  __shared__ unsigned short sorted[CAP]; // 8 KB
  __shared__ unsigned hist[128], cur[128];
  __shared__ unsigned wtot;
  int t = threadIdx.x, bkt = blockIdx.x;
  int cnt = gcnt[bkt];
  if (cnt > CAP) cnt = CAP;
  size_t ebbase = (size_t)bkt * CAP;
  if (t < 128) hist[t] = 0;
  __syncthreads();
  for (int i = t; i < cnt; i += 512) {
    unsigned e = eb[ebbase + i];
    stage[i] = e;
    atomicAdd(&hist[e >> 16], 1u);
  }
  __syncthreads();
  if (t < 128) {                         // exclusive scan of 128 node counters
    int lane = t & 63;
    unsigned v = hist[t], ss = v;
    #pragma unroll
    for (int d = 1; d < 64; d <<= 1) {
      unsigned u = __shfl_up(ss, d, 64);
      if (lane >= d) ss += u;
    }
    if (t == 63) wtot = ss;
    cur[t] = ss - v;
  }
  __syncthreads();
  if (t < 128) {
    unsigned e0 = cur[t] + (t >= 64 ? wtot : 0u);
    cur[t] = e0;
    int n = bkt * 128 + t;
    if (n < N_NODES) {
      rowlo[n] = (int)(ebbase + e0);
      rowhi[n] = (int)(ebbase + e0 + hist[t]);
    }
  }
  __syncthreads();
  for (int i = t; i < cnt; i += 512) {
    unsigned e = stage[i];
    unsigned r = atomicAdd(&cur[e >> 16], 1u);
    sorted[r] = (unsigned short)(e & 0xFFFFu);
  }
  __syncthreads();                       // sorted/cur stable from here (read-only below)

  // export sorted src list for conv2
  for (int i = t; i < cnt; i += 512) srt16[ebbase + i] = sorted[i];

  // conv1 aggregation: 32 groups x 16 lanes; group g handles dloc g, g+32, g+64, g+96
  int g = t >> 4, c = t & 15;
  for (int ii = 0; ii < 4; ++ii) {
    int dloc = ii * 32 + g;
    int node = bkt * 128 + dloc;
    if (node >= N_NODES) continue;
    int hi = (int)cur[dloc];
    int lo = hi - (int)hist[dloc];
    bf16x8 sv = *(const bf16x8*)(embb + (size_t)xidx[node] * DIM + c * 8);
    float a[8];
    #pragma unroll
    for (int e = 0; e < 8; ++e) a[e] = bf2f((unsigned short)sv[e]);
    int k = lo;
    for (; k + 8 <= hi; k += 8) {
      bf16x8 w[8];
      #pragma unroll
      for (int q = 0; q < 8; ++q)
        w[q] = *(const bf16x8*)(embb + (size_t)xidx[sorted[k + q]] * DIM + c * 8);
      #pragma unroll
      for (int q = 0; q < 8; ++q)
        #pragma unroll
        for (int e = 0; e < 8; ++e) a[e] += bf2f((unsigned short)w[q][e]);
    }
    for (; k + 2 <= hi; k += 2) {
      bf16x8 w0 = *(const bf16x8*)(embb + (size_t)xidx[sorted[k]] * DIM + c * 8);
      bf16x8 w1 = *(const bf16x8*)(embb + (size_t)xidx[sorted[k + 1]] * DIM + c * 8);
      #pragma unroll
      for (int e = 0; e < 8; ++e)
        a[e] += bf2f((unsigned short)w0[e]) + bf2f((unsigned short)w1[e]);
    }
    if (k < hi) {
      bf16x8 w = *(const bf16x8*)(embb + (size_t)xidx[sorted[k]] * DIM + c * 8);
      #pragma unroll
      for (int e = 0; e < 8; ++e) a[e] += bf2f((unsigned short)w[e]);
    }
    bf16x8 o;
    #pragma unroll
    for (int e = 0; e < 8; ++e) o[e] = (short)f2bf(a[e]);
    *(bf16x8*)(xa + (size_t)node * DIM + c * 8) = o;
  }
}

// ---------------------------------------------------------------- agg (conv2): from node features
__global__ __launch_bounds__(256) void agg_x_kernel(
    const unsigned short* __restrict__ x, const int* __restrict__ rowlo,
    const int* __restrict__ rowhi, const unsigned short* __restrict__ srt16,
    unsigned short* __restrict__ xa) {
  int n = blockIdx.x * 16 + (threadIdx.x >> 4);
  int c = threadIdx.x & 15;
  int lo = rowlo[n], hi = rowhi[n];
  bf16x8 sv = *(const bf16x8*)(x + (size_t)n * DIM + c * 8);
  float a[8];
  #pragma unroll
  for (int e = 0; e < 8; ++e) a[e] = bf2f((unsigned short)sv[e]);
  int k = lo;
  for (; k + 8 <= hi; k += 8) {
    bf16x8 w[8];
    #pragma unroll
    for (int q = 0; q < 8; ++q)
      w[q] = *(const bf16x8*)(x + (size_t)srt16[k + q] * DIM + c * 8);
    #pragma unroll
    for (int q = 0; q < 8; ++q)
      #pragma unroll
      for (int e = 0; e < 8; ++e) a[e] += bf2f((unsigned short)w[q][e]);
  }
  for (; k + 2 <= hi; k += 2) {
    bf16x8 w0 = *(const bf16x8*)(x + (size_t)srt16[k] * DIM + c * 8);
    bf16x8 w1 = *(const bf16x8*)(x + (size_t)srt16[k + 1] * DIM + c * 8);
    #pragma unroll
    for (int e = 0; e < 8; ++e)
      a[e] += bf2f((unsigned short)w0[e]) + bf2f((unsigned short)w1[e]);
  }
  if (k < hi) {
    bf16x8 w = *(const bf16x8*)(x + (size_t)srt16[k] * DIM + c * 8);
    #pragma unroll
    for (int e = 0; e < 8; ++e) a[e] += bf2f((unsigned short)w[e]);
  }
  bf16x8 o;
  #pragma unroll
  for (int e = 0; e < 8; ++e) o[e] = (short)f2bf(a[e]);
  *(bf16x8*)(xa + (size_t)n * DIM + c * 8) = o;
}

// ---------------------------------------------------------------- MLP: 256 thr, 128 nodes (2 halves)
__global__ __launch_bounds__(256) void mlp_mfma_kernel(
    const unsigned short* __restrict__ xa,
    const unsigned short* __restrict__ wabf, const float* __restrict__ ba,
    const unsigned short* __restrict__ wbbf, const float* __restrict__ bb,
    unsigned short* __restrict__ xout) {
  __shared__ short Xs[64 * 128];   // 16 KB, 16B-chunk XOR swizzle (chunk ^= row&7)
  __shared__ short Hs[64 * 128];   // 16 KB
  int t = threadIdx.x;
  int lane = t & 63;
  int w = t >> 6;
  int jq = w * 32;
  int l15 = lane & 15;
  int lg = lane >> 4;

  bf16x8 waf[2][4], wbf[2][4];
  #pragma unroll
  for (int jm = 0; jm < 2; ++jm) {
    int jrow = jq + jm * 16 + l15;
    #pragma unroll
    for (int ks = 0; ks < 4; ++ks) {
      int k0 = ks * 32 + lg * 8;
      waf[jm][ks] = *(const bf16x8*)(wabf + (size_t)jrow * DIM + k0);
      wbf[jm][ks] = *(const bf16x8*)(wbbf + (size_t)jrow * DIM + k0);
    }
  }
  f32x4 ba_r[2], bb_r[2];
  #pragma unroll
  for (int jm = 0; jm < 2; ++jm) {
    ba_r[jm] = *(const f32x4*)(ba + jq + jm * 16 + lg * 4);
    bb_r[jm] = *(const f32x4*)(bb + jq + jm * 16 + lg * 4);
  }

  for (int half = 0; half < 2; ++half) {
    int nbase = blockIdx.x * 128 + half * 64;

    {
      int r = t >> 2;
      int cb = (t & 3) * 4;
      int node = nbase + r;
      #pragma unroll
      for (int i = 0; i < 4; ++i) {
        int chunk = cb + i;
        bf16x8 v = {0, 0, 0, 0, 0, 0, 0, 0};
        if (node < N_NODES)
          v = *(const bf16x8*)(xa + (size_t)node * DIM + chunk * 8);
        *(bf16x8*)&Xs[r * 128 + ((chunk ^ (r & 7)) << 3)] = v;
      }
    }
    __syncthreads();

    #pragma unroll
    for (int nt = 0; nt < 4; ++nt) {
      int rrow = nt * 16 + l15;
      bf16x8 xf[4];
      #pragma unroll
      for (int ks = 0; ks < 4; ++ks) {
        int chunk = ks * 4 + lg;
        xf[ks] = *(const bf16x8*)&Xs[rrow * 128 + ((chunk ^ (rrow & 7)) << 3)];
      }
      #pragma unroll
      for (int jm = 0; jm < 2; ++jm) {
        f32x4 acc = ba_r[jm];
        #pragma unroll
        for (int ks = 0; ks < 4; ++ks)
          acc = __builtin_amdgcn_mfma_f32_16x16x32_bf16(waf[jm][ks], xf[ks], acc, 0, 0, 0);
        int hnode = nt * 16 + l15;
        int cbase = jq + jm * 16 + lg * 4;
        unsigned p0 = (unsigned)f2bf(fmaxf(acc[0], 0.f)) |
                      ((unsigned)f2bf(fmaxf(acc[1], 0.f)) << 16);
        unsigned p1 = (unsigned)f2bf(fmaxf(acc[2], 0.f)) |
                      ((unsigned)f2bf(fmaxf(acc[3], 0.f)) << 16);
        unsigned idx = hnode * 128 + (((cbase >> 3) ^ (hnode & 7)) << 3) + (cbase & 7);
        *(uint2*)&Hs[idx] = make_uint2(p0, p1);
      }
    }
    __syncthreads();

    #pragma unroll
    for (int nt = 0; nt < 4; ++nt) {
      int rrow = nt * 16 + l15;
      bf16x8 hf[4];
      #pragma unroll
      for (int ks = 0; ks < 4; ++ks) {
        int chunk = ks * 4 + lg;
        hf[ks] = *(const bf16x8*)&Hs[rrow * 128 + ((chunk ^ (rrow & 7)) << 3)];
      }
      #pragma unroll
      for (int jm = 0; jm < 2; ++jm) {
        f32x4 acc = bb_r[jm];
        #pragma unroll
        for (int ks = 0; ks < 4; ++ks)
          acc = __builtin_amdgcn_mfma_f32_16x16x32_bf16(wbf[jm][ks], hf[ks], acc, 0, 0, 0);
        int node = nbase + rrow;
        if (node < N_NODES) {
          bf16x4 o;
          #pragma unroll
          for (int e = 0; e < 4; ++e) o[e] = (short)f2bf(fmaxf(acc[e], 0.f));
          *(bf16x4*)(xout + (size_t)node * DIM + jq + jm * 16 + lg * 4) = o;
        }
      }
    }
    __syncthreads();   // protect Xs/Hs before next half
  }
}

// ---------------------------------------------------------------- mean-pool + FC (row-parallel)
#define PP 132
__global__ __launch_bounds__(256) void pool_fc_kernel(
    const unsigned short* __restrict__ x, const int* __restrict__ batch,
    const float* __restrict__ fcw, const float* __restrict__ fcb,
    float* __restrict__ out) {
  int g = blockIdx.x, t = threadIdx.x;
  __shared__ float part[16 * PP];
  __shared__ float pooled[DIM];
  __shared__ int sbound[2];
  if (t < 2) {
    int target = g + t;
    int lo = 0, hi = N_NODES;
    while (lo < hi) {
      int m = (lo + hi) >> 1;
      if (batch[m] < target) lo = m + 1; else hi = m;
    }
    sbound[t] = lo;
  }
  __syncthreads();
  int lo = sbound[0], hi = sbound[1];
  int r = t >> 4, c = t & 15;
  float acc[8] = {0.f, 0.f, 0.f, 0.f, 0.f, 0.f, 0.f, 0.f};
  for (int nn = lo + r; nn < hi; nn += 16) {
    bf16x8 v = *(const bf16x8*)(x + (size_t)nn * DIM + c * 8);
    #pragma unroll
    for (int e = 0; e < 8; ++e) acc[e] += bf2f((unsigned short)v[e]);
  }
  #pragma unroll
  for (int e = 0; e < 8; ++e) part[r * PP + c * 8 + e] = acc[e];
  __syncthreads();
  if (t < DIM) {
    float s = 0.f;
    #pragma unroll
    for (int rr = 0; rr < 16; ++rr) s += part[rr * PP + t];
    pooled[t] = s / fmaxf((float)(hi - lo), 1.0f);
  }
  __syncthreads();
  if (t < ODIM) {
    float a = fcb[t];
    const float* wr = fcw + (size_t)t * DIM;
    #pragma unroll 8
    for (int h = 0; h < DIM; ++h) a += pooled[h] * wr[h];
    out[(size_t)g * ODIM + t] = a;
  }
}

// ---------------------------------------------------------------- launch
extern "C" void kernel_launch(void* const* d_in, const int* in_sizes, int n_in,
                              void* d_out, int out_size, void* d_ws, size_t ws_size,
                              hipStream_t stream) {
  const float* emb  = (const float*)d_in[0];
  const float* w1a  = (const float*)d_in[1];
  const float* b1a  = (const float*)d_in[2];
  const float* w1b  = (const float*)d_in[3];
  const float* b1b  = (const float*)d_in[4];
  const float* w2a  = (const float*)d_in[5];
  const float* b2a  = (const float*)d_in[6];
  const float* w2b  = (const float*)d_in[7];
  const float* b2b  = (const float*)d_in[8];
  const float* fcw  = (const float*)d_in[9];
  const float* fcb  = (const float*)d_in[10];
  const int*   xidx = (const int*)d_in[11];
  const int*   ei   = (const int*)d_in[12];
  const int*   batch= (const int*)d_in[13];
  float* out = (float*)d_out;

  size_t featb = (size_t)N_NODES * DIM * sizeof(unsigned short);  // 12.8 MB
  char* ws = (char*)d_ws;
  unsigned short* B1 = (unsigned short*)ws;             // agg buffer
  unsigned short* B2 = (unsigned short*)(ws + featb);   // conv1 out
  char* p = ws + 2 * featb;
  unsigned short* embb = (unsigned short*)p;  p += (VOCAB * DIM * 2 + 15) / 16 * 16;
  unsigned short* wbf  = (unsigned short*)p;  p += (4 * DIM * DIM * 2 + 15) / 16 * 16;  // 128 KB
  int* gcnt  = (int*)p;     p += (NBKT * 4 + 15) / 16 * 16;
  int* rowlo = (int*)p;     p += ((size_t)N_NODES * 4 + 15) / 16 * 16;
  int* rowhi = (int*)p;     p += ((size_t)N_NODES * 4 + 15) / 16 * 16;
  unsigned* eb = (unsigned*)p;          p += (size_t)NBKT * CAP * 4;   // 6.4 MB
  unsigned short* srt16 = (unsigned short*)p;                          // 3.2 MB

  const unsigned short* w1abf = wbf;
  const unsigned short* w1bbf = wbf + DIM * DIM;
  const unsigned short* w2abf = wbf + 2 * DIM * DIM;
  const unsigned short* w2bbf = wbf + 3 * DIM * DIM;

  prep_kernel<<<(VOCAB * 16 + 4 * 2048 + 255) / 256, 256, 0, stream>>>(
      emb, w1a, w1b, w2a, w2b, embb, wbf, gcnt);

  // bucket build (count -> span-alloc -> scatter) in ONE kernel
  build_kernel<<<NB2, 512, 0, stream>>>(ei, gcnt, eb);

  // sort buckets + conv1 aggregation fused; emits srt16/rowlo/rowhi for conv2
  sort_agg1_kernel<<<NBKT, 512, 0, stream>>>(eb, gcnt, embb, xidx, srt16, rowlo, rowhi, B1);
  mlp_mfma_kernel<<<(N_NODES + 127) / 128, 256, 0, stream>>>(B1, w1abf, b1a, w1bbf, b1b, B2);

  // conv2: gather from node features, then MLP
  agg_x_kernel<<<N_NODES / 16, 256, 0, stream>>>(B2, rowlo, rowhi, srt16, B1);
  mlp_mfma_kernel<<<(N_NODES + 127) / 128, 256, 0, stream>>>(B1, w2abf, b2a, w2bbf, b2b, B2);

  pool_fc_kernel<<<NGRAPH, 256, 0, stream>>>(B2, batch, fcw, fcb, out);
}